// Round 10
// baseline (573.865 us; speedup 1.0000x reference)
//
#include <hip/hip_runtime.h>
#include <hip/hip_bf16.h>

#define B 64
#define H 128
#define E 128
#define D 20
#define P 1000
#define MP 8
#define NN 20001           // outputs per batch row
#define NODES 20002        // node slots (zero, embedding, D*P nodes)
#define HE 256
#define ROWE (B * H)       // 8192 elements per node row
#define NPB 4              // nodes per depth-block (grid = P/NPB = 250)

typedef __attribute__((ext_vector_type(8))) short bf16x8;
typedef __attribute__((ext_vector_type(4))) float f32x4;

// Node vectors stored bf16 in a device global (328 MB), plus small statics.
__device__ unsigned short g_nv[(size_t)NODES * ROWE];
__device__ float g_neproj[D * P * H];
__device__ unsigned short g_w1bf[H * H];    // left half of W1, bf16
__device__ unsigned short g_w1rbf[H * H];   // right half of W1, bf16
__device__ unsigned short g_w2bf[H * H];    // W2, bf16

// ---------------- bf16 <-> f32 helpers --------------------------------------
__device__ __forceinline__ unsigned f2bf(float f) {          // scalar RNE (cold paths)
    unsigned u = __float_as_uint(f);
    return (u + 0x7FFFu + ((u >> 16) & 1u)) >> 16;
}
__device__ __forceinline__ unsigned pk2bf(float lo, float hi) {  // v_cvt_pk_bf16_f32
    __hip_bfloat162 h = __float22bfloat162_rn(make_float2(lo, hi));
    return *reinterpret_cast<unsigned*>(&h);
}
__device__ __forceinline__ float bf2f_lo(unsigned w) { return __uint_as_float(w << 16); }
__device__ __forceinline__ float bf2f_hi(unsigned w) { return __uint_as_float(w & 0xFFFF0000u); }

// ---------------------------- init ------------------------------------------
__global__ __launch_bounds__(256) void init_kernel(
    const float* __restrict__ emb, const float* __restrict__ Wout,
    const float* __restrict__ bout, float* __restrict__ out)
{
    int blk = blockIdx.x, tid = threadIdx.x;
    if (blk < 4) {                        // nv row 0 = 0
        uint4 z = {0u, 0u, 0u, 0u};
        reinterpret_cast<uint4*>(g_nv)[blk * 256 + tid] = z;
    } else if (blk < 8) {                 // nv row 1 = bf16(embedding)
        int ch = (blk - 4) * 256 + tid;
        const float* s = emb + ch * 8;
        uint4 v;
        v.x = pk2bf(s[0], s[1]);
        v.y = pk2bf(s[2], s[3]);
        v.z = pk2bf(s[4], s[5]);
        v.w = pk2bf(s[6], s[7]);
        reinterpret_cast<uint4*>(g_nv + ROWE)[ch] = v;
    } else {                              // out[:,0] = emb @ Wout[0] + bout[0]
        if (tid < B) {
            float acc = 0.f;
            for (int h = 0; h < H; ++h) acc += emb[tid * H + h] * Wout[h];
            out[(size_t)tid * NN] = acc + bout[0];
        }
    }
}

// -------------------- weight bf16 pre-conversion ----------------------------
__global__ __launch_bounds__(256) void wprep_kernel(
    const float* __restrict__ W1, const float* __restrict__ W2)
{
    int idx = blockIdx.x * 256 + threadIdx.x;   // 0..49151
    if (idx < H * H) {
        g_w1bf[idx] = (unsigned short)f2bf(W1[(idx >> 7) * HE + (idx & 127)]);
    } else if (idx < 2 * H * H) {
        int i = idx - H * H;
        g_w1rbf[i] = (unsigned short)f2bf(W1[(i >> 7) * HE + H + (i & 127)]);
    } else {
        int i = idx - 2 * H * H;
        g_w2bf[i] = (unsigned short)f2bf(W2[i]);
    }
}

// ---------------- neproj: [D*P][H] = emb_table[idx] @ W1R^T + b1 (MFMA) ------
__global__ __launch_bounds__(256) void neproj_kernel(
    const int* __restrict__ node_indices, const float* __restrict__ emb_table,
    const float* __restrict__ b1)
{
    __shared__ unsigned short a_s[64 * 128];   // bf16 emb tile, chunk-swizzled
    const int tid = threadIdx.x;
    const int w = tid >> 6, l = tid & 63;
    const int lr = l & 15, lg = l >> 4;
    const int r0 = blockIdx.x * 64;

    // A-frags: W1R[o][k], o = w*32 + t*16 + lr, k = ks*32 + lg*8 + j
    bf16x8 aw[2][4];
    #pragma unroll
    for (int t = 0; t < 2; ++t)
        #pragma unroll
        for (int s = 0; s < 4; ++s)
            aw[t][s] = *reinterpret_cast<const bf16x8*>(
                g_w1rbf + (w * 32 + t * 16 + lr) * H + s * 32 + lg * 8);

    // stage 64 emb rows (fp32 -> bf16, swizzled)
    #pragma unroll
    for (int it = 0; it < 4; ++it) {
        int ch = tid + it * 256;          // rr = ch>>4, c = ch&15
        int rr = ch >> 4, c = ch & 15;
        int r = r0 + rr;
        int node = (r < D * P) ? node_indices[r] : 0;
        const float* s = emb_table + (size_t)node * E + c * 8;
        float4 x0 = *reinterpret_cast<const float4*>(s);
        float4 x1 = *reinterpret_cast<const float4*>(s + 4);
        uint4 v;
        v.x = pk2bf(x0.x, x0.y); v.y = pk2bf(x0.z, x0.w);
        v.z = pk2bf(x1.x, x1.y); v.w = pk2bf(x1.z, x1.w);
        *reinterpret_cast<uint4*>(a_s + rr * H + ((c ^ (rr & 7)) * 8)) = v;
    }
    __syncthreads();

    // acc init = b1[o] broadcast over rows
    f32x4 acc[2][4];
    #pragma unroll
    for (int t = 0; t < 2; ++t) {
        float4 bv = *reinterpret_cast<const float4*>(b1 + (2 * w + t) * 16 + 4 * lg);
        #pragma unroll
        for (int nt = 0; nt < 4; ++nt)
            acc[t][nt] = (f32x4){bv.x, bv.y, bv.z, bv.w};
    }
    #pragma unroll
    for (int ks = 0; ks < 4; ++ks) {
        bf16x8 pb[4];
        #pragma unroll
        for (int nt = 0; nt < 4; ++nt) {
            int b = nt * 16 + lr;
            pb[nt] = *reinterpret_cast<const bf16x8*>(
                a_s + b * H + (((ks * 4 + lg) ^ (b & 7)) * 8));
        }
        #pragma unroll
        for (int t = 0; t < 2; ++t)
            #pragma unroll
            for (int nt = 0; nt < 4; ++nt)
                acc[t][nt] = __builtin_amdgcn_mfma_f32_16x16x32_bf16(
                    aw[t][ks], pb[nt], acc[t][nt], 0, 0, 0);
    }

    // store: g_neproj[r][o0..o0+3] = acc (float4)
    #pragma unroll
    for (int t = 0; t < 2; ++t) {
        int o0 = (2 * w + t) * 16 + 4 * lg;
        #pragma unroll
        for (int nt = 0; nt < 4; ++nt) {
            int r = r0 + nt * 16 + lr;
            if (r < D * P)
                *reinterpret_cast<float4*>(g_neproj + (size_t)r * H + o0) =
                    *reinterpret_cast<float4*>(&acc[t][nt]);
        }
    }
}

// ---------------- one depth step: NPB nodes per block ------------------------
// Swapped-role GEMMs: h1^T = W1L . pv^T ; h2^T = W2 . h1^T.
// C-frag: lane l reg r -> (o = (2w+t)*16 + 4*lg + r, b = nt*16 + lr).
// Weight fragment sets (W1L, W2) resident in registers for the whole block;
// all NPB nodes' parent row offsets hoisted to block start (SGPRs).
__global__ __launch_bounds__(256) void depth_kernel(
    const int* __restrict__ parent_indices,  // [D][P][MP]
    const float* __restrict__ b2v,           // [H]
    const float* __restrict__ Wout,          // [NN][H]
    const float* __restrict__ bout,          // [NN]
    float* __restrict__ out,                 // [B][NN]
    int d)
{
    __shared__ unsigned short pv_s[64 * 128];   // bf16, chunk-swizzled
    __shared__ unsigned short h1_s[64 * 128];   // bf16, chunk-swizzled; reused for node
    const int tid = threadIdx.x;
    const int w = tid >> 6, l = tid & 63;
    const int lr = l & 15, lg = l >> 4;
    const int p0 = blockIdx.x * NPB;

    // ---- load both weight A-frag sets once (resident across nodes) ----
    bf16x8 aw1[2][4], aw2[2][4];
    #pragma unroll
    for (int t = 0; t < 2; ++t)
        #pragma unroll
        for (int s = 0; s < 4; ++s) {
            aw1[t][s] = *reinterpret_cast<const bf16x8*>(
                g_w1bf + (w * 32 + t * 16 + lr) * H + s * 32 + lg * 8);
            aw2[t][s] = *reinterpret_cast<const bf16x8*>(
                g_w2bf + (w * 32 + t * 16 + lr) * H + s * 32 + lg * 8);
        }

    // ---- hoist all NPB nodes' parent row offsets (32-bit elem offsets, SGPR)
    const int* par0 = parent_indices + ((size_t)d * P + p0) * MP;
    unsigned roff[NPB][MP];
    #pragma unroll
    for (int i = 0; i < NPB; ++i)
        #pragma unroll
        for (int m = 0; m < MP; ++m)
            roff[i][m] = (unsigned)__builtin_amdgcn_readfirstlane(par0[i * MP + m])
                         * (unsigned)ROWE;

    for (int i = 0; i < NPB; ++i) {
        const int p = p0 + i;

        // ---- gather: pv[b][h] = sum_m bf16(nv[parent_m])[b][h], fp32 accum --
        #pragma unroll
        for (int it = 0; it < 4; ++it) {
            int ch = tid + it * 256;             // chunk: b = ch>>4, c = ch&15
            float a0 = 0.f, a1 = 0.f, a2 = 0.f, a3 = 0.f,
                  a4 = 0.f, a5 = 0.f, a6 = 0.f, a7 = 0.f;
            #pragma unroll
            for (int m = 0; m < MP; ++m) {
                uint4 v = reinterpret_cast<const uint4*>(g_nv + roff[i][m])[ch];
                a0 += bf2f_lo(v.x); a1 += bf2f_hi(v.x);
                a2 += bf2f_lo(v.y); a3 += bf2f_hi(v.y);
                a4 += bf2f_lo(v.z); a5 += bf2f_hi(v.z);
                a6 += bf2f_lo(v.w); a7 += bf2f_hi(v.w);
            }
            int b = ch >> 4, c = ch & 15;
            uint4 ov;
            ov.x = pk2bf(a0, a1); ov.y = pk2bf(a2, a3);
            ov.z = pk2bf(a4, a5); ov.w = pk2bf(a6, a7);
            *reinterpret_cast<uint4*>(pv_s + b * H + ((c ^ (b & 7)) * 8)) = ov;
        }
        __syncthreads();

        // ---- GEMM1: h1^T = W1L . pv^T + neproj (relu) ----
        const float* np_row = g_neproj + (size_t)(d * P + p) * H;
        f32x4 acc[2][4];
        #pragma unroll
        for (int t = 0; t < 2; ++t) {
            float4 nv4 = *reinterpret_cast<const float4*>(np_row + (2 * w + t) * 16 + 4 * lg);
            #pragma unroll
            for (int nt = 0; nt < 4; ++nt)
                acc[t][nt] = (f32x4){nv4.x, nv4.y, nv4.z, nv4.w};
        }
        #pragma unroll
        for (int ks = 0; ks < 4; ++ks) {
            bf16x8 pb[4];
            #pragma unroll
            for (int nt = 0; nt < 4; ++nt) {
                int b = nt * 16 + lr;
                pb[nt] = *reinterpret_cast<const bf16x8*>(
                    pv_s + b * H + (((ks * 4 + lg) ^ (b & 7)) * 8));
            }
            #pragma unroll
            for (int t = 0; t < 2; ++t)
                #pragma unroll
                for (int nt = 0; nt < 4; ++nt)
                    acc[t][nt] = __builtin_amdgcn_mfma_f32_16x16x32_bf16(
                        aw1[t][ks], pb[nt], acc[t][nt], 0, 0, 0);
        }
        // relu + packed h1 store (b64 per (t,nt))
        #pragma unroll
        for (int t = 0; t < 2; ++t) {
            int o0 = (2 * w + t) * 16 + 4 * lg;
            #pragma unroll
            for (int nt = 0; nt < 4; ++nt) {
                int b = nt * 16 + lr;
                float v0 = fmaxf(acc[t][nt][0], 0.f);
                float v1 = fmaxf(acc[t][nt][1], 0.f);
                float v2 = fmaxf(acc[t][nt][2], 0.f);
                float v3 = fmaxf(acc[t][nt][3], 0.f);
                uint2 pk; pk.x = pk2bf(v0, v1); pk.y = pk2bf(v2, v3);
                *reinterpret_cast<uint2*>(
                    h1_s + b * H + ((o0 >> 3) ^ (b & 7)) * 8 + (o0 & 7)) = pk;
            }
        }
        __syncthreads();

        // ---- GEMM2: h2^T = W2 . h1^T + b2 ----
        #pragma unroll
        for (int t = 0; t < 2; ++t) {
            float4 bv = *reinterpret_cast<const float4*>(b2v + (2 * w + t) * 16 + 4 * lg);
            #pragma unroll
            for (int nt = 0; nt < 4; ++nt)
                acc[t][nt] = (f32x4){bv.x, bv.y, bv.z, bv.w};
        }
        #pragma unroll
        for (int ks = 0; ks < 4; ++ks) {
            bf16x8 pb[4];
            #pragma unroll
            for (int nt = 0; nt < 4; ++nt) {
                int b = nt * 16 + lr;
                pb[nt] = *reinterpret_cast<const bf16x8*>(
                    h1_s + b * H + (((ks * 4 + lg) ^ (b & 7)) * 8));
            }
            #pragma unroll
            for (int t = 0; t < 2; ++t)
                #pragma unroll
                for (int nt = 0; nt < 4; ++nt)
                    acc[t][nt] = __builtin_amdgcn_mfma_f32_16x16x32_bf16(
                        aw2[t][ks], pb[nt], acc[t][nt], 0, 0, 0);
        }
        __syncthreads();   // all h1_s reads done before overwrite

        // ---- epilogue: node = pv + h2 -> h1_s (packed b64) ----
        #pragma unroll
        for (int t = 0; t < 2; ++t) {
            int o0 = (2 * w + t) * 16 + 4 * lg;
            #pragma unroll
            for (int nt = 0; nt < 4; ++nt) {
                int b = nt * 16 + lr;
                int off = b * H + ((o0 >> 3) ^ (b & 7)) * 8 + (o0 & 7);
                uint2 pv2 = *reinterpret_cast<const uint2*>(pv_s + off);
                float v0 = bf2f_lo(pv2.x) + acc[t][nt][0];
                float v1 = bf2f_hi(pv2.x) + acc[t][nt][1];
                float v2 = bf2f_lo(pv2.y) + acc[t][nt][2];
                float v3 = bf2f_hi(pv2.y) + acc[t][nt][3];
                uint2 pk; pk.x = pk2bf(v0, v1); pk.y = pk2bf(v2, v3);
                *reinterpret_cast<uint2*>(h1_s + off) = pk;
            }
        }
        __syncthreads();

        // ---- write node row to g_nv (unswizzle, coalesced b128) ----
        int node = 2 + d * P + p;
        uint4* nvrow = reinterpret_cast<uint4*>(g_nv + (size_t)node * ROWE);
        #pragma unroll
        for (int it = 0; it < 4; ++it) {
            int idx = tid + it * 256;          // idx = b*16 + c
            int b = idx >> 4, c = idx & 15;
            nvrow[idx] = *reinterpret_cast<const uint4*>(h1_s + b * H + ((c ^ (b & 7)) * 8));
        }

        // ---- out[b][n] = node[b] . Wout[n] + bout[n],  n = 1 + d*P + p ----
        int n_out = 1 + d * P + p;
        const float* wr = Wout + (size_t)n_out * H;
        int ob = tid >> 2, q = tid & 3;
        float partial = 0.f;
        #pragma unroll
        for (int c4 = 0; c4 < 4; ++c4) {
            int c = q * 4 + c4;
            uint4 v = *reinterpret_cast<const uint4*>(h1_s + ob * H + ((c ^ (ob & 7)) * 8));
            int h0 = c * 8;
            float4 w0 = *reinterpret_cast<const float4*>(wr + h0);
            float4 w1 = *reinterpret_cast<const float4*>(wr + h0 + 4);
            partial += bf2f_lo(v.x) * w0.x + bf2f_hi(v.x) * w0.y
                     + bf2f_lo(v.y) * w0.z + bf2f_hi(v.y) * w0.w
                     + bf2f_lo(v.z) * w1.x + bf2f_hi(v.z) * w1.y
                     + bf2f_lo(v.w) * w1.z + bf2f_hi(v.w) * w1.w;
        }
        partial += __shfl_xor(partial, 1);
        partial += __shfl_xor(partial, 2);
        if (q == 0) out[(size_t)ob * NN + n_out] = partial + bout[n_out];
        __syncthreads();   // pv_s/h1_s free for next node
    }
}

extern "C" void kernel_launch(void* const* d_in, const int* in_sizes, int n_in,
                              void* d_out, int out_size, void* d_ws, size_t ws_size,
                              hipStream_t stream) {
    const float* embedding      = (const float*)d_in[0];
    const int*   node_indices   = (const int*)d_in[1];
    const int*   parent_indices = (const int*)d_in[2];
    const float* emb_table      = (const float*)d_in[3];
    const float* W1             = (const float*)d_in[4];
    const float* b1             = (const float*)d_in[5];
    const float* W2             = (const float*)d_in[6];
    const float* b2             = (const float*)d_in[7];
    const float* Wout           = (const float*)d_in[8];
    const float* bout           = (const float*)d_in[9];
    float* out = (float*)d_out;
    (void)d_ws; (void)ws_size;

    init_kernel<<<9, 256, 0, stream>>>(embedding, Wout, bout, out);
    wprep_kernel<<<192, 256, 0, stream>>>(W1, W2);
    neproj_kernel<<<(D * P + 63) / 64, 256, 0, stream>>>(node_indices, emb_table, b1);
    for (int d = 0; d < D; ++d) {
        depth_kernel<<<P / NPB, 256, 0, stream>>>(parent_indices, b2, Wout, bout, out, d);
    }
}

// Round 11
// 491.075 us; speedup vs baseline: 1.1686x; 1.1686x over previous
//
#include <hip/hip_runtime.h>
#include <hip/hip_bf16.h>

#define B 64
#define H 128
#define E 128
#define D 20
#define P 1000
#define MP 8
#define NN 20001           // outputs per batch row
#define NODES 20002        // node slots (zero, embedding, D*P nodes)
#define HE 256
#define ROWE (B * H)       // 8192 elements per node row
#define NPB 2              // nodes per depth-block (grid = P/NPB = 500)

typedef __attribute__((ext_vector_type(8))) short bf16x8;
typedef __attribute__((ext_vector_type(4))) float f32x4;

// Node vectors stored bf16 in a device global (328 MB), plus small statics.
__device__ unsigned short g_nv[(size_t)NODES * ROWE];
__device__ float g_neproj[D * P * H];
__device__ unsigned short g_w1bf[H * H];    // left half of W1, bf16
__device__ unsigned short g_w1rbf[H * H];   // right half of W1, bf16
__device__ unsigned short g_w2bf[H * H];    // W2, bf16

// ---------------- bf16 <-> f32 helpers --------------------------------------
__device__ __forceinline__ unsigned f2bf(float f) {          // scalar RNE (cold paths)
    unsigned u = __float_as_uint(f);
    return (u + 0x7FFFu + ((u >> 16) & 1u)) >> 16;
}
__device__ __forceinline__ unsigned pk2bf(float lo, float hi) {  // v_cvt_pk_bf16_f32
    __hip_bfloat162 h = __float22bfloat162_rn(make_float2(lo, hi));
    return *reinterpret_cast<unsigned*>(&h);
}
__device__ __forceinline__ float bf2f_lo(unsigned w) { return __uint_as_float(w << 16); }
__device__ __forceinline__ float bf2f_hi(unsigned w) { return __uint_as_float(w & 0xFFFF0000u); }

// ---------------------------- init ------------------------------------------
__global__ __launch_bounds__(256) void init_kernel(
    const float* __restrict__ emb, const float* __restrict__ Wout,
    const float* __restrict__ bout, float* __restrict__ out)
{
    int blk = blockIdx.x, tid = threadIdx.x;
    if (blk < 4) {                        // nv row 0 = 0
        uint4 z = {0u, 0u, 0u, 0u};
        reinterpret_cast<uint4*>(g_nv)[blk * 256 + tid] = z;
    } else if (blk < 8) {                 // nv row 1 = bf16(embedding)
        int ch = (blk - 4) * 256 + tid;
        const float* s = emb + ch * 8;
        uint4 v;
        v.x = pk2bf(s[0], s[1]);
        v.y = pk2bf(s[2], s[3]);
        v.z = pk2bf(s[4], s[5]);
        v.w = pk2bf(s[6], s[7]);
        reinterpret_cast<uint4*>(g_nv + ROWE)[ch] = v;
    } else {                              // out[:,0] = emb @ Wout[0] + bout[0]
        if (tid < B) {
            float acc = 0.f;
            for (int h = 0; h < H; ++h) acc += emb[tid * H + h] * Wout[h];
            out[(size_t)tid * NN] = acc + bout[0];
        }
    }
}

// -------------------- weight bf16 pre-conversion ----------------------------
__global__ __launch_bounds__(256) void wprep_kernel(
    const float* __restrict__ W1, const float* __restrict__ W2)
{
    int idx = blockIdx.x * 256 + threadIdx.x;   // 0..49151
    if (idx < H * H) {
        g_w1bf[idx] = (unsigned short)f2bf(W1[(idx >> 7) * HE + (idx & 127)]);
    } else if (idx < 2 * H * H) {
        int i = idx - H * H;
        g_w1rbf[i] = (unsigned short)f2bf(W1[(i >> 7) * HE + H + (i & 127)]);
    } else {
        int i = idx - 2 * H * H;
        g_w2bf[i] = (unsigned short)f2bf(W2[i]);
    }
}

// ---------------- neproj: [D*P][H] = emb_table[idx] @ W1R^T + b1 (MFMA) ------
__global__ __launch_bounds__(256) void neproj_kernel(
    const int* __restrict__ node_indices, const float* __restrict__ emb_table,
    const float* __restrict__ b1)
{
    __shared__ unsigned short a_s[64 * 128];   // bf16 emb tile, chunk-swizzled
    const int tid = threadIdx.x;
    const int w = tid >> 6, l = tid & 63;
    const int lr = l & 15, lg = l >> 4;
    const int r0 = blockIdx.x * 64;

    // A-frags: W1R[o][k], o = w*32 + t*16 + lr, k = ks*32 + lg*8 + j
    bf16x8 aw[2][4];
    #pragma unroll
    for (int t = 0; t < 2; ++t)
        #pragma unroll
        for (int s = 0; s < 4; ++s)
            aw[t][s] = *reinterpret_cast<const bf16x8*>(
                g_w1rbf + (w * 32 + t * 16 + lr) * H + s * 32 + lg * 8);

    // stage 64 emb rows (fp32 -> bf16, swizzled)
    #pragma unroll
    for (int it = 0; it < 4; ++it) {
        int ch = tid + it * 256;          // rr = ch>>4, c = ch&15
        int rr = ch >> 4, c = ch & 15;
        int r = r0 + rr;
        int node = (r < D * P) ? node_indices[r] : 0;
        const float* s = emb_table + (size_t)node * E + c * 8;
        float4 x0 = *reinterpret_cast<const float4*>(s);
        float4 x1 = *reinterpret_cast<const float4*>(s + 4);
        uint4 v;
        v.x = pk2bf(x0.x, x0.y); v.y = pk2bf(x0.z, x0.w);
        v.z = pk2bf(x1.x, x1.y); v.w = pk2bf(x1.z, x1.w);
        *reinterpret_cast<uint4*>(a_s + rr * H + ((c ^ (rr & 7)) * 8)) = v;
    }
    __syncthreads();

    // acc init = b1[o] broadcast over rows
    f32x4 acc[2][4];
    #pragma unroll
    for (int t = 0; t < 2; ++t) {
        float4 bv = *reinterpret_cast<const float4*>(b1 + (2 * w + t) * 16 + 4 * lg);
        #pragma unroll
        for (int nt = 0; nt < 4; ++nt)
            acc[t][nt] = (f32x4){bv.x, bv.y, bv.z, bv.w};
    }
    #pragma unroll
    for (int ks = 0; ks < 4; ++ks) {
        bf16x8 pb[4];
        #pragma unroll
        for (int nt = 0; nt < 4; ++nt) {
            int b = nt * 16 + lr;
            pb[nt] = *reinterpret_cast<const bf16x8*>(
                a_s + b * H + (((ks * 4 + lg) ^ (b & 7)) * 8));
        }
        #pragma unroll
        for (int t = 0; t < 2; ++t)
            #pragma unroll
            for (int nt = 0; nt < 4; ++nt)
                acc[t][nt] = __builtin_amdgcn_mfma_f32_16x16x32_bf16(
                    aw[t][ks], pb[nt], acc[t][nt], 0, 0, 0);
    }

    // store: g_neproj[r][o0..o0+3] = acc (float4)
    #pragma unroll
    for (int t = 0; t < 2; ++t) {
        int o0 = (2 * w + t) * 16 + 4 * lg;
        #pragma unroll
        for (int nt = 0; nt < 4; ++nt) {
            int r = r0 + nt * 16 + lr;
            if (r < D * P)
                *reinterpret_cast<float4*>(g_neproj + (size_t)r * H + o0) =
                    *reinterpret_cast<float4*>(&acc[t][nt]);
        }
    }
}

// ---------------- one depth step: NPB nodes per block ------------------------
// Swapped-role GEMMs: h1^T = W1L . pv^T ; h2^T = W2 . h1^T.
// C-frag: lane l reg r -> (o = (2w+t)*16 + 4*lg + r, b = nt*16 + lr).
// Both weight fragment sets (W1L, W2) stay resident in registers for the
// whole block: weight traffic = 64 KB per block (NPB nodes), not per node.
__global__ __launch_bounds__(256) void depth_kernel(
    const int* __restrict__ parent_indices,  // [D][P][MP]
    const float* __restrict__ b2v,           // [H]
    const float* __restrict__ Wout,          // [NN][H]
    const float* __restrict__ bout,          // [NN]
    float* __restrict__ out,                 // [B][NN]
    int d)
{
    __shared__ unsigned short pv_s[64 * 128];   // bf16, chunk-swizzled
    __shared__ unsigned short h1_s[64 * 128];   // bf16, chunk-swizzled; reused for node
    const int tid = threadIdx.x;
    const int w = tid >> 6, l = tid & 63;
    const int lr = l & 15, lg = l >> 4;

    // ---- load both weight A-frag sets once (resident across nodes) ----
    bf16x8 aw1[2][4], aw2[2][4];
    #pragma unroll
    for (int t = 0; t < 2; ++t)
        #pragma unroll
        for (int s = 0; s < 4; ++s) {
            aw1[t][s] = *reinterpret_cast<const bf16x8*>(
                g_w1bf + (w * 32 + t * 16 + lr) * H + s * 32 + lg * 8);
            aw2[t][s] = *reinterpret_cast<const bf16x8*>(
                g_w2bf + (w * 32 + t * 16 + lr) * H + s * 32 + lg * 8);
        }

    for (int i = 0; i < NPB; ++i) {
        const int p = blockIdx.x * NPB + i;

        // ---- gather: pv[b][h] = sum_m bf16(nv[parent_m])[b][h], fp32 accum --
        const int* par = parent_indices + ((size_t)d * P + p) * MP;
        size_t roff[MP];
        #pragma unroll
        for (int m = 0; m < MP; ++m)
            roff[m] = (size_t)__builtin_amdgcn_readfirstlane(par[m]) * ROWE;

        #pragma unroll
        for (int it = 0; it < 4; ++it) {
            int ch = tid + it * 256;             // chunk: b = ch>>4, c = ch&15
            float a0 = 0.f, a1 = 0.f, a2 = 0.f, a3 = 0.f,
                  a4 = 0.f, a5 = 0.f, a6 = 0.f, a7 = 0.f;
            #pragma unroll
            for (int m = 0; m < MP; ++m) {
                uint4 v = reinterpret_cast<const uint4*>(g_nv + roff[m])[ch];
                a0 += bf2f_lo(v.x); a1 += bf2f_hi(v.x);
                a2 += bf2f_lo(v.y); a3 += bf2f_hi(v.y);
                a4 += bf2f_lo(v.z); a5 += bf2f_hi(v.z);
                a6 += bf2f_lo(v.w); a7 += bf2f_hi(v.w);
            }
            int b = ch >> 4, c = ch & 15;
            uint4 ov;
            ov.x = pk2bf(a0, a1); ov.y = pk2bf(a2, a3);
            ov.z = pk2bf(a4, a5); ov.w = pk2bf(a6, a7);
            *reinterpret_cast<uint4*>(pv_s + b * H + ((c ^ (b & 7)) * 8)) = ov;
        }
        __syncthreads();

        // ---- GEMM1: h1^T = W1L . pv^T + neproj (relu) ----
        const float* np_row = g_neproj + (size_t)(d * P + p) * H;
        f32x4 acc[2][4];
        #pragma unroll
        for (int t = 0; t < 2; ++t) {
            float4 nv4 = *reinterpret_cast<const float4*>(np_row + (2 * w + t) * 16 + 4 * lg);
            #pragma unroll
            for (int nt = 0; nt < 4; ++nt)
                acc[t][nt] = (f32x4){nv4.x, nv4.y, nv4.z, nv4.w};
        }
        #pragma unroll
        for (int ks = 0; ks < 4; ++ks) {
            bf16x8 pb[4];
            #pragma unroll
            for (int nt = 0; nt < 4; ++nt) {
                int b = nt * 16 + lr;
                pb[nt] = *reinterpret_cast<const bf16x8*>(
                    pv_s + b * H + (((ks * 4 + lg) ^ (b & 7)) * 8));
            }
            #pragma unroll
            for (int t = 0; t < 2; ++t)
                #pragma unroll
                for (int nt = 0; nt < 4; ++nt)
                    acc[t][nt] = __builtin_amdgcn_mfma_f32_16x16x32_bf16(
                        aw1[t][ks], pb[nt], acc[t][nt], 0, 0, 0);
        }
        // relu + packed h1 store (b64 per (t,nt))
        #pragma unroll
        for (int t = 0; t < 2; ++t) {
            int o0 = (2 * w + t) * 16 + 4 * lg;
            #pragma unroll
            for (int nt = 0; nt < 4; ++nt) {
                int b = nt * 16 + lr;
                float v0 = fmaxf(acc[t][nt][0], 0.f);
                float v1 = fmaxf(acc[t][nt][1], 0.f);
                float v2 = fmaxf(acc[t][nt][2], 0.f);
                float v3 = fmaxf(acc[t][nt][3], 0.f);
                uint2 pk; pk.x = pk2bf(v0, v1); pk.y = pk2bf(v2, v3);
                *reinterpret_cast<uint2*>(
                    h1_s + b * H + ((o0 >> 3) ^ (b & 7)) * 8 + (o0 & 7)) = pk;
            }
        }
        __syncthreads();

        // ---- GEMM2: h2^T = W2 . h1^T + b2 ----
        #pragma unroll
        for (int t = 0; t < 2; ++t) {
            float4 bv = *reinterpret_cast<const float4*>(b2v + (2 * w + t) * 16 + 4 * lg);
            #pragma unroll
            for (int nt = 0; nt < 4; ++nt)
                acc[t][nt] = (f32x4){bv.x, bv.y, bv.z, bv.w};
        }
        #pragma unroll
        for (int ks = 0; ks < 4; ++ks) {
            bf16x8 pb[4];
            #pragma unroll
            for (int nt = 0; nt < 4; ++nt) {
                int b = nt * 16 + lr;
                pb[nt] = *reinterpret_cast<const bf16x8*>(
                    h1_s + b * H + (((ks * 4 + lg) ^ (b & 7)) * 8));
            }
            #pragma unroll
            for (int t = 0; t < 2; ++t)
                #pragma unroll
                for (int nt = 0; nt < 4; ++nt)
                    acc[t][nt] = __builtin_amdgcn_mfma_f32_16x16x32_bf16(
                        aw2[t][ks], pb[nt], acc[t][nt], 0, 0, 0);
        }
        __syncthreads();   // all h1_s reads done before overwrite

        // ---- epilogue: node = pv + h2 -> h1_s (packed b64) ----
        #pragma unroll
        for (int t = 0; t < 2; ++t) {
            int o0 = (2 * w + t) * 16 + 4 * lg;
            #pragma unroll
            for (int nt = 0; nt < 4; ++nt) {
                int b = nt * 16 + lr;
                int off = b * H + ((o0 >> 3) ^ (b & 7)) * 8 + (o0 & 7);
                uint2 pv2 = *reinterpret_cast<const uint2*>(pv_s + off);
                float v0 = bf2f_lo(pv2.x) + acc[t][nt][0];
                float v1 = bf2f_hi(pv2.x) + acc[t][nt][1];
                float v2 = bf2f_lo(pv2.y) + acc[t][nt][2];
                float v3 = bf2f_hi(pv2.y) + acc[t][nt][3];
                uint2 pk; pk.x = pk2bf(v0, v1); pk.y = pk2bf(v2, v3);
                *reinterpret_cast<uint2*>(h1_s + off) = pk;
            }
        }
        __syncthreads();

        // ---- write node row to g_nv (unswizzle, coalesced b128) ----
        int node = 2 + d * P + p;
        uint4* nvrow = reinterpret_cast<uint4*>(g_nv + (size_t)node * ROWE);
        #pragma unroll
        for (int it = 0; it < 4; ++it) {
            int idx = tid + it * 256;          // idx = b*16 + c
            int b = idx >> 4, c = idx & 15;
            nvrow[idx] = *reinterpret_cast<const uint4*>(h1_s + b * H + ((c ^ (b & 7)) * 8));
        }

        // ---- out[b][n] = node[b] . Wout[n] + bout[n],  n = 1 + d*P + p ----
        int n_out = 1 + d * P + p;
        const float* wr = Wout + (size_t)n_out * H;
        int ob = tid >> 2, q = tid & 3;
        float partial = 0.f;
        #pragma unroll
        for (int c4 = 0; c4 < 4; ++c4) {
            int c = q * 4 + c4;
            uint4 v = *reinterpret_cast<const uint4*>(h1_s + ob * H + ((c ^ (ob & 7)) * 8));
            int h0 = c * 8;
            float4 w0 = *reinterpret_cast<const float4*>(wr + h0);
            float4 w1 = *reinterpret_cast<const float4*>(wr + h0 + 4);
            partial += bf2f_lo(v.x) * w0.x + bf2f_hi(v.x) * w0.y
                     + bf2f_lo(v.y) * w0.z + bf2f_hi(v.y) * w0.w
                     + bf2f_lo(v.z) * w1.x + bf2f_hi(v.z) * w1.y
                     + bf2f_lo(v.w) * w1.z + bf2f_hi(v.w) * w1.w;
        }
        partial += __shfl_xor(partial, 1);
        partial += __shfl_xor(partial, 2);
        if (q == 0) out[(size_t)ob * NN + n_out] = partial + bout[n_out];
        __syncthreads();   // pv_s/h1_s free for next node
    }
}

extern "C" void kernel_launch(void* const* d_in, const int* in_sizes, int n_in,
                              void* d_out, int out_size, void* d_ws, size_t ws_size,
                              hipStream_t stream) {
    const float* embedding      = (const float*)d_in[0];
    const int*   node_indices   = (const int*)d_in[1];
    const int*   parent_indices = (const int*)d_in[2];
    const float* emb_table      = (const float*)d_in[3];
    const float* W1             = (const float*)d_in[4];
    const float* b1             = (const float*)d_in[5];
    const float* W2             = (const float*)d_in[6];
    const float* b2             = (const float*)d_in[7];
    const float* Wout           = (const float*)d_in[8];
    const float* bout           = (const float*)d_in[9];
    float* out = (float*)d_out;
    (void)d_ws; (void)ws_size;

    init_kernel<<<9, 256, 0, stream>>>(embedding, Wout, bout, out);
    wprep_kernel<<<192, 256, 0, stream>>>(W1, W2);
    neproj_kernel<<<(D * P + 63) / 64, 256, 0, stream>>>(node_indices, emb_table, b1);
    for (int d = 0; d < D; ++d) {
        depth_kernel<<<P / NPB, 256, 0, stream>>>(parent_indices, b2, Wout, bout, out, d);
    }
}